// Round 7
// baseline (674.482 us; speedup 1.0000x reference)
//
#include <hip/hip_runtime.h>

typedef _Float16 f16;
typedef f16 f16x8 __attribute__((ext_vector_type(8)));
typedef float f32x4 __attribute__((ext_vector_type(4)));

static constexpr int NDATA = 50000;
static constexpr int DF    = 3072;
static constexpr int BP    = 256;
static constexpr int NGRPQ = 792;     // 64-row softmax groups (792*64 = 50688)
static constexpr int NW    = 50688;   // W row stride / padded N

// workspace offsets (bytes)
static constexpr size_t OFF_W  = 0;            // W : 256*50688*2 = 25952256
static constexpr size_t OFF_XH = 25952256;     // xh: 1572864
static constexpr size_t OFF_MP = 27525120;     // Mp: 792*256*4 = 811008
static constexpr size_t OFF_LP = 28336128;     // Lp: 811008
static constexpr size_t OFF_M  = 29147136;     // M : 1024
static constexpr size_t OFF_L  = 29148160;     // L : 1024
static constexpr size_t OFF_P  = 29149184;     // P : nch * 3145728
static constexpr size_t SLAB   = (size_t)BP * DF * 4;

// lgkm-only barrier: LDS ordered, global loads stay IN FLIGHT (no vmcnt drain)
__device__ __forceinline__ void barrier_lgkm() {
  __builtin_amdgcn_sched_barrier(0);
  asm volatile("s_waitcnt lgkmcnt(0)" ::: "memory");
  __builtin_amdgcn_s_barrier();
  __builtin_amdgcn_sched_barrier(0);
}

// ---------------- K1: x -> fp16 ----------------
__global__ void k_prep_x(const float* __restrict__ x, f16* __restrict__ xh) {
  int i = blockIdx.x * 256 + threadIdx.x;
  f32x4 v = ((const f32x4*)x)[i];
  union { f16 f[4]; short4 s; } u;
  u.f[0] = (f16)v[0]; u.f[1] = (f16)v[1]; u.f[2] = (f16)v[2]; u.f[3] = (f16)v[3];
  ((short4*)xh)[i] = u.s;
}

// ---------------- K2: S-tile via MFMA -> per-group softmax partials + W' ----------------
// 256 thr (4 waves), tile 64n x 128b (wave 16n x 128b, acc[8]), K-step 32.
// grid 1584 = 792 n-groups x 2 b-halves; XCD swizzle pairs the halves (A shared via L2).
__global__ __launch_bounds__(256) void k_qk(const float* __restrict__ data,
                                            const f16* __restrict__ xh,
                                            const float* __restrict__ sigma,
                                            f16* __restrict__ W,
                                            float* __restrict__ Mp,
                                            float* __restrict__ Lp) {
  __shared__ char smem[31232];
  f16 (*As)[2560] = (f16(*)[2560])smem;              // 2 x [64][40] f16 (5120 B each)
  f16 (*Bs)[5120] = (f16(*)[5120])(smem + 10240);    // 2 x [128][40] f16 (10240 B each)
  float* dn_s = (float*)(smem + 30720);              // [64]
  float* m4   = (float*)smem;                        // alias: [4][128]
  float* l4   = (float*)(smem + 2048);               // alias: [4][128]
  float* m_s  = (float*)(smem + 4096);               // alias: [128]
  f16*  trans = (f16*)(smem + 10240);                // alias: [128][72] (18432 B)

  const int tid = threadIdx.x;
  const int wid = tid >> 6, lane = tid & 63;
  const int l15 = lane & 15, kg = lane >> 4;
  const int bid = blockIdx.x;
  const int swz = (bid & 7) * 198 + (bid >> 3);      // 1584 = 8*198, bijective
  const int g   = swz >> 1;                          // n-group
  const int bh  = swz & 1;                           // b-half
  const int n0  = g * 64;

  // A staging: row = tid>>2 (64 rows), 8 floats at (tid&3)*8
  const int arow = tid >> 2, ak = (tid & 3) * 8;
  const int agr = n0 + arow;
  const float* ap = data + (size_t)(agr < NDATA ? agr : NDATA - 1) * DF + ak;
  // B staging: row = tid>>1 (128 rows of this b-half), 16 f16 at (tid&1)*16
  const int brow = tid >> 1, bk = (tid & 1) * 16;
  const f16* bp = xh + (size_t)(bh * 128 + brow) * DF + bk;

  f32x4 acc[8] = {};
  float sq = 0.f;
  f32x4 aA0, aA1, aB0, aB1;
  f16x8 bA0, bA1, bB0, bB1;

  auto gloadA = [&](int k0, f32x4& a0, f32x4& a1) {
    a0 = *(const f32x4*)(ap + k0);
    a1 = *(const f32x4*)(ap + k0 + 4);
  };
  auto gloadB = [&](int k0, f16x8& b0, f16x8& b1) {
    b0 = *(const f16x8*)(bp + k0);
    b1 = *(const f16x8*)(bp + k0 + 8);
  };
  auto swrite = [&](int buf, f32x4& a0, f32x4& a1, f16x8& b0, f16x8& b1) {
    f16x8 h;
#pragma unroll
    for (int j = 0; j < 4; ++j) {
      h[j] = (f16)a0[j];     sq = fmaf(a0[j], a0[j], sq);
      h[4 + j] = (f16)a1[j]; sq = fmaf(a1[j], a1[j], sq);
    }
    *(f16x8*)(&As[buf][arow * 40 + ak]) = h;
    *(f16x8*)(&Bs[buf][brow * 40 + bk]) = b0;
    *(f16x8*)(&Bs[buf][brow * 40 + bk + 8]) = b1;
  };
  auto compute = [&](int buf) {
    f16x8 af = *(const f16x8*)(&As[buf][(wid * 16 + l15) * 40 + kg * 8]);
#pragma unroll
    for (int c = 0; c < 8; ++c) {
      f16x8 bf = *(const f16x8*)(&Bs[buf][(c * 16 + l15) * 40 + kg * 8]);
      acc[c] = __builtin_amdgcn_mfma_f32_16x16x32_f16(af, bf, acc[c], 0, 0, 0);
    }
  };

  gloadA(0, aA0, aA1); gloadB(0, bA0, bA1);
  swrite(0, aA0, aA1, bA0, bA1);
  gloadA(32, aB0, aB1); gloadB(32, bB0, bB1);
  barrier_lgkm();

  for (int ks = 0; ks < 96; ks += 2) {
    if (ks + 2 < 96) { gloadA((ks + 2) * 32, aA0, aA1); gloadB((ks + 2) * 32, bA0, bA1); }
    compute(0);
    swrite(1, aB0, aB1, bB0, bB1);
    barrier_lgkm();
    if (ks + 3 < 96) { gloadA((ks + 3) * 32, aB0, aB1); gloadB((ks + 3) * 32, bB0, bB1); }
    compute(1);
    if (ks + 2 < 96) swrite(0, aA0, aA1, bA0, bA1);
    barrier_lgkm();
  }

  // |d|^2: reduce across the 4 staging threads of each row
  sq += __shfl_xor(sq, 1);
  sq += __shfl_xor(sq, 2);
  if ((tid & 3) == 0) dn_s[arow] = sq;
  __syncthreads();

  const float sg  = sigma[0];
  const float inv = 0.5f / (sg * sg);
  float dn[4];
  bool ok[4];
#pragma unroll
  for (int r = 0; r < 4; ++r) {
    const int rl = wid * 16 + kg * 4 + r;      // C/D: row=(l>>4)*4+reg
    dn[r] = dn_s[rl];
    ok[r] = (n0 + rl) < NDATA;
  }

  // pass 1: block-local column max over the 64 rows
  float pm[8];
#pragma unroll
  for (int c = 0; c < 8; ++c) pm[c] = -1e30f;
#pragma unroll
  for (int r = 0; r < 4; ++r)
#pragma unroll
    for (int c = 0; c < 8; ++c) {
      float v = ok[r] ? (2.f * acc[c][r] - dn[r]) * inv : -1e30f;
      pm[c] = fmaxf(pm[c], v);
    }
#pragma unroll
  for (int c = 0; c < 8; ++c) {
    pm[c] = fmaxf(pm[c], __shfl_xor(pm[c], 16));
    pm[c] = fmaxf(pm[c], __shfl_xor(pm[c], 32));
  }
  if (kg == 0) {
#pragma unroll
    for (int c = 0; c < 8; ++c) m4[wid * 128 + c * 16 + l15] = pm[c];
  }
  __syncthreads();
  if (tid < 128)
    m_s[tid] = fmaxf(fmaxf(m4[tid], m4[128 + tid]), fmaxf(m4[256 + tid], m4[384 + tid]));
  __syncthreads();

  float mcol[8];
#pragma unroll
  for (int c = 0; c < 8; ++c) mcol[c] = m_s[c * 16 + l15];

  // pass 2: w = exp(v - m_grp), accumulate l, transposed store
  float pl[8] = {};
#pragma unroll
  for (int r = 0; r < 4; ++r) {
    const int rl = wid * 16 + kg * 4 + r;
#pragma unroll
    for (int c = 0; c < 8; ++c) {
      float v = (2.f * acc[c][r] - dn[r]) * inv;
      float w = ok[r] ? __expf(v - mcol[c]) : 0.f;
      pl[c] += w;
      trans[(c * 16 + l15) * 72 + rl] = (f16)w;
    }
  }
#pragma unroll
  for (int c = 0; c < 8; ++c) {
    pl[c] += __shfl_xor(pl[c], 16);
    pl[c] += __shfl_xor(pl[c], 32);
  }
  if (kg == 0) {
#pragma unroll
    for (int c = 0; c < 8; ++c) l4[wid * 128 + c * 16 + l15] = pl[c];
  }
  __syncthreads();
  if (tid < 128) {
    Mp[g * 256 + bh * 128 + tid] = m_s[tid];
    Lp[g * 256 + bh * 128 + tid] = l4[tid] + l4[128 + tid] + l4[256 + tid] + l4[384 + tid];
  }
  // transpose readout -> W' (64 contiguous f16 per column)
  {
    const int col = tid >> 1, q = tid & 1;
    const f16* src = trans + col * 72 + q * 32;
    f16* dst = W + (size_t)(bh * 128 + col) * NW + n0 + q * 32;
#pragma unroll
    for (int j = 0; j < 4; ++j)
      *(f16x8*)(dst + j * 8) = *(const f16x8*)(src + j * 8);
  }
}

// ---------------- K3: combine partials -> M[b], L[b] ----------------
__global__ void k_comb(const float* __restrict__ Mp, const float* __restrict__ Lp,
                       float* __restrict__ M, float* __restrict__ L, int ngrp) {
  __shared__ float ms[4][256], ls[4][256];
  const int tid = threadIdx.x;
  const int q = tid >> 8, b = tid & 255;
  float m = -1e38f, l = 0.f;
  for (int g = q; g < ngrp; g += 4) {
    float m2 = Mp[g * 256 + b], l2 = Lp[g * 256 + b];
    if (m2 > m) { l = l * __expf(m - m2) + l2; m = m2; }
    else        { l += l2 * __expf(m2 - m); }
  }
  ms[q][b] = m; ls[q][b] = l;
  __syncthreads();
  if (q == 0) {
#pragma unroll
    for (int j = 1; j < 4; ++j) {
      float m2 = ms[j][b], l2 = ls[j][b];
      if (m2 > m) { l = l * __expf(m - m2) + l2; m = m2; }
      else        { l += l2 * __expf(m2 - m); }
    }
    M[b] = m; L[b] = l;
  }
}

// ---------------- K4: eps partials = (W*exp(Mp-M)) @ data, split-K over n ----------------
// 256 thr (4 waves), tile 128b x 64d (wave 32b x 64d), K-step 32.
// grid = 96*nch; swizzle pairs the two b-halves of each (chunk,dt) on one XCD.
__global__ __launch_bounds__(256) void k_pv(const float* __restrict__ data,
                                            const f16* __restrict__ W,
                                            const float* __restrict__ Mp,
                                            const float* __restrict__ M,
                                            float* __restrict__ part,
                                            int chn, int per8) {
  __shared__ uint32_t T[2][64 * 20];   // [d][n-pair(16)+pad4] packed f16 pairs
  const int tid = threadIdx.x;
  const int wid = tid >> 6, lane = tid & 63;
  const int l15 = lane & 15, kg = lane >> 4;
  const int bid = blockIdx.x;
  const int swz = (bid & 7) * per8 + (bid >> 3);
  const int chunk = swz / 96;
  const int r96 = swz % 96;
  const int dt = r96 >> 1, bh = r96 & 1;
  const int d0 = dt * 64;
  const int nstart = chunk * chn;
  const int kst = chn >> 5;
  const int np = tid >> 4;            // n-pair 0..15
  const int d4 = (tid & 15) * 4;      // d 0..60 step 4

  f32x4 acc[2][4] = {};
  const int b0 = bh * 128 + wid * 32 + l15, b1 = b0 + 16;
  const float Mb0 = M[b0], Mb1 = M[b1];
  const f16* wp0 = W + (size_t)b0 * NW + nstart + kg * 8;
  const f16* wp1 = W + (size_t)b1 * NW + nstart + kg * 8;

  f32x4 gaA, gbA, gaB, gbB;
  f16x8 w0c, w1c, w0n, w1n;
  float mpAc, mpBc, mpAn, mpBn;

  auto gload = [&](int ks, f32x4& ga, f32x4& gb) {
    int n = nstart + ks * 32 + np * 2;
    int na = n < NDATA ? n : NDATA - 1;           // tail rows have W==0
    int nb = (n + 1) < NDATA ? (n + 1) : NDATA - 1;
    ga = *(const f32x4*)(data + (size_t)na * DF + d0 + d4);
    gb = *(const f32x4*)(data + (size_t)nb * DF + d0 + d4);
  };
  auto wload = [&](int ks, f16x8& w0, f16x8& w1, float& ma, float& mb) {
    w0 = *(const f16x8*)(wp0 + ks * 32);
    w1 = *(const f16x8*)(wp1 + ks * 32);
    int gq = (nstart + ks * 32) >> 6;
    ma = Mp[gq * 256 + b0];
    mb = Mp[gq * 256 + b1];
  };
  auto twrite = [&](int buf, f32x4& ga, f32x4& gb) {
#pragma unroll
    for (int j = 0; j < 4; ++j) {
      int d = d4 + j;
      int pn = np ^ (((d >> 3) & 3) << 2);        // pair-unit bank swizzle
      union { f16 f[2]; uint32_t u; } u;
      u.f[0] = (f16)ga[j]; u.f[1] = (f16)gb[j];
      T[buf][d * 20 + pn] = u.u;
    }
  };
  auto compute = [&](int buf, f16x8& w0, f16x8& w1, float ma, float mb) {
    f16 h0 = (f16)__expf(ma - Mb0);
    f16 h1 = (f16)__expf(mb - Mb1);
    f16x8 a0, a1;
#pragma unroll
    for (int j = 0; j < 8; ++j) { a0[j] = w0[j] * h0; a1[j] = w1[j] * h1; }
#pragma unroll
    for (int c = 0; c < 4; ++c) {
      int d = c * 16 + l15;
      int dw = d * 20 + ((kg * 4) ^ (((d >> 3) & 3) << 2));
      f16x8 bf = *(const f16x8*)(&T[buf][dw]);
      acc[0][c] = __builtin_amdgcn_mfma_f32_16x16x32_f16(a0, bf, acc[0][c], 0, 0, 0);
      acc[1][c] = __builtin_amdgcn_mfma_f32_16x16x32_f16(a1, bf, acc[1][c], 0, 0, 0);
    }
  };

  gload(0, gaA, gbA);
  wload(0, w0c, w1c, mpAc, mpBc);
  twrite(0, gaA, gbA);
  gload(1, gaB, gbB);
  barrier_lgkm();

  for (int ks = 0; ks < kst; ks += 2) {
    if (ks + 2 < kst) gload(ks + 2, gaA, gbA);
    if (ks + 1 < kst) wload(ks + 1, w0n, w1n, mpAn, mpBn);
    compute(0, w0c, w1c, mpAc, mpBc);
    if (ks + 1 < kst) twrite(1, gaB, gbB);
    barrier_lgkm();
    if (ks + 1 < kst) {
      if (ks + 3 < kst) gload(ks + 3, gaB, gbB);
      if (ks + 2 < kst) wload(ks + 2, w0c, w1c, mpAc, mpBc);
      compute(1, w0n, w1n, mpAn, mpBn);
      if (ks + 2 < kst) twrite(0, gaA, gbA);
      barrier_lgkm();
    }
  }

  float* pp = part + (size_t)chunk * (BP * DF);
#pragma unroll
  for (int i = 0; i < 2; ++i)
#pragma unroll
    for (int c = 0; c < 4; ++c)
#pragma unroll
      for (int r = 0; r < 4; ++r) {
        int b = bh * 128 + wid * 32 + i * 16 + kg * 4 + r;
        int d = d0 + c * 16 + l15;
        pp[(size_t)b * DF + d] = acc[i][c][r];
      }
}

// ---------------- K5: out = (x - (sum partials)/L) / sigma ----------------
__global__ void k_final(const float* __restrict__ x, const float* __restrict__ sigma,
                        const float* __restrict__ part, const float* __restrict__ L,
                        float* __restrict__ out, int nch) {
  int i = blockIdx.x * 256 + threadIdx.x;
  int b = (i * 4) / DF;
  f32x4 s = {};
  for (int c = 0; c < nch; ++c) s += ((const f32x4*)(part + (size_t)c * BP * DF))[i];
  f32x4 xv = ((const f32x4*)x)[i];
  float invL = 1.f / L[b];
  float invsg = 1.f / sigma[0];
  f32x4 r;
#pragma unroll
  for (int j = 0; j < 4; ++j) r[j] = (xv[j] - s[j] * invL) * invsg;
  ((f32x4*)out)[i] = r;
}

extern "C" void kernel_launch(void* const* d_in, const int* in_sizes, int n_in,
                              void* d_out, int out_size, void* d_ws, size_t ws_size,
                              hipStream_t stream) {
  const float* x     = (const float*)d_in[0];
  const float* sigma = (const float*)d_in[1];
  const float* data  = (const float*)d_in[2];
  float* out = (float*)d_out;
  char* ws = (char*)d_ws;

  f16*   W  = (f16*)(ws + OFF_W);
  f16*   xh = (f16*)(ws + OFF_XH);
  float* Mp = (float*)(ws + OFF_MP);
  float* Lp = (float*)(ws + OFF_LP);
  float* M  = (float*)(ws + OFF_M);
  float* L  = (float*)(ws + OFF_L);
  float* P  = (float*)(ws + OFF_P);

  int nch = 24, chn = 2112;                         // 24*2112 = 50688 exactly
  if (ws_size < OFF_P + 24 * SLAB) { nch = 16; chn = 3168; }
  if (ws_size < OFF_P + 16 * SLAB) { nch = 8;  chn = 6336; }
  const int grid_pv = 96 * nch;
  const int per8 = grid_pv / 8;

  k_prep_x<<<768, 256, 0, stream>>>(x, xh);
  k_qk<<<NGRPQ * 2, 256, 0, stream>>>(data, xh, sigma, W, Mp, Lp);
  k_comb<<<1, 1024, 0, stream>>>(Mp, Lp, M, L, NGRPQ);
  k_pv<<<grid_pv, 256, 0, stream>>>(data, W, Mp, M, P, chn, per8);
  k_final<<<768, 256, 0, stream>>>(x, sigma, P, L, out, nch);
}